// Round 7
// baseline (617.976 us; speedup 1.0000x reference)
//
#include <hip/hip_runtime.h>

typedef float f32x4  __attribute__((ext_vector_type(4)));
typedef _Float16 f16x8  __attribute__((ext_vector_type(8)));
typedef _Float16 f16x4v __attribute__((ext_vector_type(4)));
typedef _Float16 f16x8v __attribute__((ext_vector_type(8)));

__device__ inline void load_lds16(const _Float16* g, _Float16* l) {
    __builtin_amdgcn_global_load_lds((const __attribute__((address_space(1))) void*)g,
                                     (__attribute__((address_space(3))) void*)l, 16, 0, 0);
}

// ---------------------------------------------------------------------------
// convert_h: fp32 -> fp16 (hi only; A-side operands need no lo term)
// ---------------------------------------------------------------------------
__global__ __launch_bounds__(256)
void convert_h(const float* __restrict__ X, _Float16* __restrict__ H, long n4)
{
    long i = (long)blockIdx.x * 256 + threadIdx.x;
    if (i >= n4) return;
    f32x4 v = ((const f32x4*)X)[i];
    f16x4v h;
#pragma unroll
    for (int k = 0; k < 4; ++k) h[k] = (_Float16)v[k];
    ((f16x4v*)H)[i] = h;
}

// ---------------------------------------------------------------------------
// transpose_w3: W [D][D] fp32 -> Wt [n][k] fp16 hi (+lo for z<2) in ONE dispatch
// ---------------------------------------------------------------------------
__global__ __launch_bounds__(256)
void transpose_w3(const float* __restrict__ Wq, const float* __restrict__ Wk,
                  const float* __restrict__ Wv,
                  _Float16* __restrict__ Hqk, _Float16* __restrict__ Lqk,
                  _Float16* __restrict__ Hv, int D)
{
    const int z = blockIdx.z;
    const float* W = (z == 0) ? Wq : (z == 1) ? Wk : Wv;
    _Float16* Th = (z == 0) ? Hqk : (z == 1) ? Hqk + (long)D * D : Hv;
    _Float16* Tl = (z == 0) ? Lqk : (z == 1) ? Lqk + (long)D * D : nullptr;

    __shared__ float t[32][33];
    const int tid = threadIdx.x;
    const int bx = blockIdx.x * 32, by = blockIdx.y * 32;
    const int c = tid & 31, r0 = tid >> 5;
#pragma unroll
    for (int r = r0; r < 32; r += 8)
        t[r][c] = W[(long)(by + r) * D + bx + c];
    __syncthreads();
#pragma unroll
    for (int r = r0; r < 32; r += 8) {
        float v = t[c][r];                       // = W[by+c][bx+r]
        _Float16 h = (_Float16)v;
        Th[(long)(bx + r) * D + by + c] = h;     // Wt[n=bx+r][k=by+c]
        if (z < 2) Tl[(long)(bx + r) * D + by + c] = (_Float16)(v - (float)h);
    }
}

// ---------------------------------------------------------------------------
// proj_fused: one dispatch for all projections. grid = (24, 64).
//   ct 0..7  : Q proj, 2-term (x_h @ (W_h+W_l)) -> Q_h fp16 [M][1024]
//   ct 8..15 : K proj, 2-term -> K_h + K_l fp16 [M][1024] (split storage)
//   ct 16..23: V proj, 1-term -> Vt fp16 [B][D][S] (transposed epilogue)
// 128x128 tile, BK=32, 16x16x32 f16 MFMA, global_load_lds width-16 staging.
// __launch_bounds__(256,5): VGPR<=102, LDS 32KB -> 5 blocks/CU.
// ---------------------------------------------------------------------------
constexpr int TM = 128;

__global__ __launch_bounds__(256, 5)
void proj_fused(const _Float16* __restrict__ x_h,
                const _Float16* __restrict__ Wqk_h, const _Float16* __restrict__ Wqk_l,
                const _Float16* __restrict__ Wv_h,
                _Float16* __restrict__ Q_h, _Float16* __restrict__ K_h,
                _Float16* __restrict__ K_l, _Float16* __restrict__ Vt,
                const float* __restrict__ bq, const float* __restrict__ bk,
                const float* __restrict__ bv)
{
    constexpr int D = 1024, SEQ = 2048, TK = 32;
    const int ct = blockIdx.x, rt = blockIdx.y;
    const bool qk = ct < 16;
    const int row0 = rt * TM;
    const int col0 = (qk ? ct : ct - 16) * TM;   // column in stacked-W space

    __shared__ __align__(16) _Float16 smem[16384];   // 32 KB, aliased
    _Float16* sA  = smem;            // x hi       (8 KB)
    _Float16* sBh = smem + 4096;     // W hi       (8 KB)
    _Float16* sBl = smem + 8192;     // W lo       (8 KB)

    const int tid = threadIdx.x;
    const int lane = tid & 63, wave = tid >> 6;
    const int l16 = lane & 15, quad = lane >> 4;
    const int wm = (wave >> 1) * 64, wn = (wave & 1) * 64;

    f32x4 acc[4][4] = {};

    if (qk) {
        for (int k0 = 0; k0 < D; k0 += TK) {
#pragma unroll
            for (int rnd = 0; rnd < 2; ++rnd) {
                const int row = rnd * 64 + (tid >> 2);
                const long gA = (long)(row0 + row) * D + k0 + (tid & 3) * 8;
                const long gB = (long)(col0 + row) * D + k0 + (tid & 3) * 8;
                const int lofs = rnd * 2048 + tid * 8;
                load_lds16(x_h + gA, sA + lofs);
                load_lds16(Wqk_h + gB, sBh + lofs);
                load_lds16(Wqk_l + gB, sBl + lofs);
            }
            __syncthreads();
            f16x8 a[4], b_h[4], b_l[4];
#pragma unroll
            for (int i = 0; i < 4; ++i)
                a[i] = *(const f16x8*)&sA[(wm + i * 16 + l16) * TK + (quad << 3)];
#pragma unroll
            for (int j = 0; j < 4; ++j) {
                b_h[j] = *(const f16x8*)&sBh[(wn + j * 16 + l16) * TK + (quad << 3)];
                b_l[j] = *(const f16x8*)&sBl[(wn + j * 16 + l16) * TK + (quad << 3)];
            }
#pragma unroll
            for (int i = 0; i < 4; ++i)
#pragma unroll
                for (int j = 0; j < 4; ++j) {
                    acc[i][j] = __builtin_amdgcn_mfma_f32_16x16x32_f16(a[i], b_h[j], acc[i][j], 0, 0, 0);
                    acc[i][j] = __builtin_amdgcn_mfma_f32_16x16x32_f16(a[i], b_l[j], acc[i][j], 0, 0, 0);
                }
            __syncthreads();
        }
        // epilogue: Q (hi only) or K (hi + lo)
        const bool isQ = col0 < D;
#pragma unroll
        for (int j = 0; j < 4; ++j) {
            const int col = col0 + wn + j * 16 + l16;
            const int cc = isQ ? col : col - D;
            const float bval = isQ ? bq[cc] : bk[cc];
#pragma unroll
            for (int i = 0; i < 4; ++i) {
                const int rb = row0 + wm + i * 16 + quad * 4;
#pragma unroll
                for (int r = 0; r < 4; ++r) {
                    const float v = acc[i][j][r] + bval;
                    const _Float16 h = (_Float16)v;
                    if (isQ) {
                        Q_h[(long)(rb + r) * D + cc] = h;
                    } else {
                        K_h[(long)(rb + r) * D + cc] = h;
                        K_l[(long)(rb + r) * D + cc] = (_Float16)(v - (float)h);
                    }
                }
            }
        }
    } else {
        for (int k0 = 0; k0 < D; k0 += TK) {
#pragma unroll
            for (int rnd = 0; rnd < 2; ++rnd) {
                const int row = rnd * 64 + (tid >> 2);
                const long gA = (long)(row0 + row) * D + k0 + (tid & 3) * 8;
                const long gB = (long)(col0 + row) * D + k0 + (tid & 3) * 8;
                const int lofs = rnd * 2048 + tid * 8;
                load_lds16(x_h + gA, sA + lofs);
                load_lds16(Wv_h + gB, sBh + lofs);
            }
            __syncthreads();
            f16x8 a[4], b[4];
#pragma unroll
            for (int i = 0; i < 4; ++i)
                a[i] = *(const f16x8*)&sA[(wm + i * 16 + l16) * TK + (quad << 3)];
#pragma unroll
            for (int j = 0; j < 4; ++j)
                b[j] = *(const f16x8*)&sBh[(wn + j * 16 + l16) * TK + (quad << 3)];
#pragma unroll
            for (int i = 0; i < 4; ++i)
#pragma unroll
                for (int j = 0; j < 4; ++j)
                    acc[i][j] = __builtin_amdgcn_mfma_f32_16x16x32_f16(a[i], b[j], acc[i][j], 0, 0, 0);
            __syncthreads();
        }
        // epilogue: transpose via XOR-swizzled LDS (aliases staging), 16B stores
        _Float16* sVt = smem;   // full 128x128 fp16 tile = 32 KB
#pragma unroll
        for (int j = 0; j < 4; ++j) {
            const int cl_ = wn + j * 16 + l16;
            const float bval = bv[col0 + cl_];
#pragma unroll
            for (int i = 0; i < 4; ++i) {
#pragma unroll
                for (int r = 0; r < 4; ++r) {
                    const int sl = wm + i * 16 + quad * 4 + r;
                    sVt[cl_ * TM + (sl ^ ((cl_ & 15) << 3))] = (_Float16)(acc[i][j][r] + bval);
                }
            }
        }
        __syncthreads();
        const int bb = row0 / SEQ;                 // tiles never cross batches
        const int sbase = row0 - bb * SEQ;
        for (int idx = tid; idx < TM * TM / 8; idx += 256) {
            const int cl_ = idx >> 4, s0 = (idx & 15) << 3;
            f16x8v v = *(const f16x8v*)&sVt[cl_ * TM + (s0 ^ ((cl_ & 15) << 3))];
            *(f16x8v*)&Vt[(long)bb * D * SEQ + (long)(col0 + cl_) * SEQ + sbase + s0] = v;
        }
    }
}

// ---------------------------------------------------------------------------
// gemm2: C = A @ B^T_layout (fp32 out). A fp16 [M][K] (hi only),
// B fp16 [N][K] hi (+ lo if BLO: 2-term accumulate). TM=128 x TNB, BK-wide
// K-steps (BK=64: half the barriers of BK=32).
// MODE 1: causal packed triangular grid (x = live-tile id, TNB=64);
// MODE 2: PV, grid (x=rows heavy-first, y=cols), K bounded at (rt+1)*TM.
// ---------------------------------------------------------------------------
template<bool BLO, int MODE, int TNB, int BK>
__global__ __launch_bounds__(256, 5)
void gemm2(const _Float16* __restrict__ Ah, long sA, int lda,
           const _Float16* __restrict__ Bh, const _Float16* __restrict__ Bl,
           long sB, int ldb,
           float* __restrict__ Cf, long sC, int ldc, int K)
{
    static_assert(MODE != 1 || TNB == 64, "packed causal decode assumes TNB=64");
    constexpr int NFJ = TNB / 32;       // B fragments per wave
    constexpr int ARNDS = TM * BK / 2048;
    constexpr int BRNDS = TNB * BK / 2048;
    constexpr int KS = BK / 32;         // 32-wide MFMA substeps per K-step
    constexpr int RPR = 2048 / BK;      // rows staged per round
    constexpr int KDIV = BK / 8;        // lanes per row in staging

    int rt, ct;
    if (MODE == 1) {
        const int t = blockIdx.x;
        rt = (int)((sqrtf(4.0f * t + 1.0f) - 1.0f) * 0.5f);
        while (rt * (rt + 1) > t) --rt;
        while ((rt + 1) * (rt + 2) <= t) ++rt;
        ct = t - rt * (rt + 1);
    } else {
        rt = (gridDim.x - 1) - blockIdx.x;   // heavy rows first
        ct = blockIdx.y;
    }
    const int bz = blockIdx.z;

    const _Float16* gAh = Ah + (long)bz * sA;
    const _Float16* gBh = Bh + (long)bz * sB;
    const _Float16* gBl = BLO ? Bl + (long)bz * sB : nullptr;

    const int row0 = rt * TM, col0 = ct * TNB;
    const int k_end = (MODE == 2) ? min(K, (rt + 1) * TM) : K;

    __shared__ _Float16 sAh[TM * BK];
    __shared__ _Float16 sBh[TNB * BK];
    __shared__ _Float16 sBl[BLO ? TNB * BK : 8];

    const int tid = threadIdx.x;
    const int lane = tid & 63, wave = tid >> 6;
    const int l16 = lane & 15, quad = lane >> 4;
    const int wm = (wave >> 1) * 64, wn = (wave & 1) * (TNB / 2);
    const int srow = tid / KDIV, sko = (tid % KDIV) * 8;   // staging coords

    f32x4 acc[4][NFJ] = {};

    for (int k0 = 0; k0 < k_end; k0 += BK) {
#pragma unroll
        for (int rnd = 0; rnd < ARNDS; ++rnd) {
            const int row = rnd * RPR + srow;
            const long gA = (long)(row0 + row) * lda + k0 + sko;
            load_lds16(gAh + gA, sAh + rnd * 2048 + tid * 8);
        }
#pragma unroll
        for (int rnd = 0; rnd < BRNDS; ++rnd) {
            const int row = rnd * RPR + srow;
            const long gB = (long)(col0 + row) * ldb + k0 + sko;
            const int lofs = rnd * 2048 + tid * 8;
            load_lds16(gBh + gB, sBh + lofs);
            if (BLO) load_lds16(gBl + gB, sBl + lofs);
        }
        __syncthreads();

#pragma unroll
        for (int ks = 0; ks < KS; ++ks) {
            f16x8 a[4], b_h[NFJ];
#pragma unroll
            for (int i = 0; i < 4; ++i)
                a[i] = *(const f16x8*)&sAh[(wm + i * 16 + l16) * BK + ks * 32 + (quad << 3)];
#pragma unroll
            for (int j = 0; j < NFJ; ++j)
                b_h[j] = *(const f16x8*)&sBh[(wn + j * 16 + l16) * BK + ks * 32 + (quad << 3)];

            if (BLO) {
                f16x8 b_l[NFJ];
#pragma unroll
                for (int j = 0; j < NFJ; ++j)
                    b_l[j] = *(const f16x8*)&sBl[(wn + j * 16 + l16) * BK + ks * 32 + (quad << 3)];
#pragma unroll
                for (int i = 0; i < 4; ++i)
#pragma unroll
                    for (int j = 0; j < NFJ; ++j) {
                        acc[i][j] = __builtin_amdgcn_mfma_f32_16x16x32_f16(a[i], b_h[j], acc[i][j], 0, 0, 0);
                        acc[i][j] = __builtin_amdgcn_mfma_f32_16x16x32_f16(a[i], b_l[j], acc[i][j], 0, 0, 0);
                    }
            } else {
#pragma unroll
                for (int i = 0; i < 4; ++i)
#pragma unroll
                    for (int j = 0; j < NFJ; ++j)
                        acc[i][j] = __builtin_amdgcn_mfma_f32_16x16x32_f16(a[i], b_h[j], acc[i][j], 0, 0, 0);
            }
        }
        __syncthreads();
    }

    float* cf = Cf + (long)bz * sC;
#pragma unroll
    for (int j = 0; j < NFJ; ++j) {
        const int col = col0 + wn + j * 16 + l16;
#pragma unroll
        for (int i = 0; i < 4; ++i) {
            const int rb = row0 + wm + i * 16 + quad * 4;
#pragma unroll
            for (int r = 0; r < 4; ++r)
                cf[(long)(rb + r) * ldc + col] = acc[i][j][r];
        }
    }
}

// ---------------------------------------------------------------------------
// softmax: causal, fp32 Sc row -> fp16 P row; wave-shuffle reductions,
// writes exactly the columns the PV GEMM will read (ceil((r+1)/128)*128).
// ---------------------------------------------------------------------------
__global__ __launch_bounds__(256)
void softmax_kernel(const float* __restrict__ Sc, _Float16* __restrict__ P, int seq)
{
    const int r = blockIdx.x, b = blockIdx.y;
    const float* row = Sc + ((long)b * seq + r) * seq;
    _Float16* prow = P + ((long)b * seq + r) * seq;
    const int tid = threadIdx.x;
    const int wave = tid >> 6;
    const int cmax = ((r >> 7) + 1) << 7;
    const int c0 = tid * 8;

    float v[8];
    f32x4 v0, v1;
    if (c0 <= r) {                 // chunk has at least one live column
        const f32x4* rp = (const f32x4*)row;
        v0 = rp[tid * 2];
        v1 = rp[tid * 2 + 1];
    } else {
        v0 = (f32x4)(-3.0e38f);
        v1 = (f32x4)(-3.0e38f);
    }
    float lmax = -3.0e38f;
#pragma unroll
    for (int k = 0; k < 4; ++k) {
        v[k]     = (c0 + k     <= r) ? v0[k] : -3.0e38f;
        v[k + 4] = (c0 + k + 4 <= r) ? v1[k] : -3.0e38f;
    }
#pragma unroll
    for (int k = 0; k < 8; ++k) lmax = fmaxf(lmax, v[k]);

    __shared__ float red[8];
#pragma unroll
    for (int off = 32; off > 0; off >>= 1)
        lmax = fmaxf(lmax, __shfl_xor(lmax, off, 64));
    if ((tid & 63) == 0) red[wave] = lmax;
    __syncthreads();
    const float m = fmaxf(fmaxf(red[0], red[1]), fmaxf(red[2], red[3]));

    float lsum = 0.0f;
#pragma unroll
    for (int k = 0; k < 8; ++k) {
        float e = (v[k] > -1.0e38f) ? __expf(v[k] - m) : 0.0f;
        v[k] = e;
        lsum += e;
    }
#pragma unroll
    for (int off = 32; off > 0; off >>= 1)
        lsum += __shfl_xor(lsum, off, 64);
    if ((tid & 63) == 0) red[4 + wave] = lsum;
    __syncthreads();
    const float inv = 1.0f / (red[4] + red[5] + red[6] + red[7]);

    if (c0 < cmax) {
        f16x8v o;
#pragma unroll
        for (int k = 0; k < 8; ++k) o[k] = (_Float16)(v[k] * inv);
        ((f16x8v*)prow)[tid] = o;
    }
}

// ---------------------------------------------------------------------------
extern "C" void kernel_launch(void* const* d_in, const int* in_sizes, int n_in,
                              void* d_out, int out_size, void* d_ws, size_t ws_size,
                              hipStream_t stream)
{
    constexpr int B = 4, S = 2048, D = 1024;
    constexpr long MB = 1024 * 1024;
    const float* x  = (const float*)d_in[0];
    const float* Wq = (const float*)d_in[1];
    const float* bq = (const float*)d_in[2];
    const float* Wk = (const float*)d_in[3];
    const float* bk = (const float*)d_in[4];
    const float* Wv = (const float*)d_in[5];
    const float* bv = (const float*)d_in[6];
    float* out = (float*)d_out;

    // workspace layout (160 MB; Sc overlaps dead x/W regions)
    char* ws = (char*)d_ws;
    _Float16* x_h    = (_Float16*)(ws + 0);         // 16 MB
    _Float16* Wqkt_h = (_Float16*)(ws + 16 * MB);   // 4 MB [2048][1024]
    _Float16* Wqkt_l = (_Float16*)(ws + 20 * MB);   // 4 MB
    _Float16* Wvt_h  = (_Float16*)(ws + 24 * MB);   // 2 MB
    float*    Sc     = (float*)(ws + 0);            // 64 MB, after x/W dead
    _Float16* Q_h    = (_Float16*)(ws + 64 * MB);   // 16 MB [M][1024]
    _Float16* K_h    = (_Float16*)(ws + 80 * MB);   // 16 MB
    _Float16* K_l    = (_Float16*)(ws + 96 * MB);   // 16 MB
    _Float16* Vt     = (_Float16*)(ws + 112 * MB);  // 16 MB [B][D][S]
    _Float16* P      = (_Float16*)(ws + 128 * MB);  // 32 MB [B][S][S]

    const int M = B * S;  // 8192
    dim3 blk(256);

    // 1) convert x -> fp16 hi (A-side needs no lo)
    convert_h<<<(M * D / 4 + 255) / 256, blk, 0, stream>>>(x, x_h, (long)M * D / 4);
    // 2) all weight transposes in one dispatch (Wq,Wk hi+lo stacked; Wv hi)
    transpose_w3<<<dim3(D / 32, D / 32, 3), blk, 0, stream>>>(
        Wq, Wk, Wv, Wqkt_h, Wqkt_l, Wvt_h, D);

    // 3) fused projections: Q (ct 0..7), K (ct 8..15), V (ct 16..23)
    proj_fused<<<dim3(24, M / TM), blk, 0, stream>>>(
        x_h, Wqkt_h, Wqkt_l, Wvt_h, Q_h, K_h, K_l, Vt, bq, bk, bv);

    // 4) scores = Q_h @ (K_h + K_l)^T (2-term, packed triangular, BK=64) -> fp32
    const int ntiles = (S / TM) * (S / TM + 1);   // 272 live 128x64 tiles
    gemm2<true, 1, 64, 64><<<dim3(ntiles, 1, B), blk, 0, stream>>>(
        Q_h, (long)S * D, D, K_h, K_l, (long)S * D, D,
        Sc, (long)S * S, S, D);

    // 5) causal softmax: fp32 Sc -> fp16 P
    softmax_kernel<<<dim3(S, B), blk, 0, stream>>>(Sc, P, S);

    // 6) out = P @ V (K bounded at diagonal, heavy rows first, BK=64)
    gemm2<false, 2, 64, 64><<<dim3(S / TM, D / 64, B), blk, 0, stream>>>(
        P, (long)S * S, S, Vt, nullptr, (long)D * S, S,
        out, (long)S * D, D, S);
}